// Round 3
// baseline (429.670 us; speedup 1.0000x reference)
//
#include <hip/hip_runtime.h>
#include <math.h>

#define Bn 4
#define Nn 2048
#define Hn 8
#define HDn 32
#define Dn 256
#define MQ 512  // m-split: 4 partials merged in oproj

typedef _Float16 h1;
typedef __attribute__((ext_vector_type(8))) _Float16 h8;
typedef __attribute__((ext_vector_type(4))) float fx4;

#define QSCALE 0.35355339059327373f  // 2/sqrt(HD): folded into topo at load
// |S_raw| <= HD = 32, |S_raw*QSCALE*topo| <= 11.32 -> fixed softmax shift safe:
// p = e^{S-4} in [2.2e-7, 1503] -- fits f16, no running max needed.
#define SOFTMAX_SHIFT 4.0f

// ---------------------------------------------------------------------------
// Kernel 0: transpose weights to f16  WT[w][out][d]  (w: 0=q,1=k,2=v)
// ---------------------------------------------------------------------------
__global__ __launch_bounds__(256) void cvtW_kernel(
    const float* __restrict__ Wq, const float* __restrict__ Wk,
    const float* __restrict__ Wv, h1* __restrict__ WT)
{
    const int idx = blockIdx.x * 256 + threadIdx.x;  // 3*65536
    const int o = idx & 255;
    const int d = (idx >> 8) & 255;
    const int w = idx >> 16;
    const float* W = (w == 0) ? Wq : (w == 1) ? Wk : Wv;
    WT[(size_t)w * 65536 + o * 256 + d] = (h1)W[d * 256 + o];
}

// ---------------------------------------------------------------------------
// Kernel 1: QKV projection via f16 MFMA (x split hi/lo for ~f32 accuracy)
// Block = 4 waves x 16 rows = 64 rows x 256 cols of ONE W (grid.y selects).
// Epilogue: q/k -> sincos features (unscaled); v -> LDS transpose -> vT.
// Fragment layouts (verified gfx950):
//   A: A[m=lane&15][k=quad*8+j], B: B[k=quad*8+j][n=lane&15],
//   C/D: row=quad*4+reg, col=lane&15
// ---------------------------------------------------------------------------
__global__ __launch_bounds__(256, 2) void proj_kernel(
    const float* __restrict__ x, const h1* __restrict__ WT,
    const float* __restrict__ bq, const float* __restrict__ bk,
    const float* __restrict__ bv,
    h1* __restrict__ fq, h1* __restrict__ fk, h1* __restrict__ vT)
{
    __shared__ h1 vst[64][264];  // v transpose buffer (pad 264: 2-way free)
    const int tid = threadIdx.x;
    const int w = tid >> 6;
    const int lane = tid & 63;
    const int quad = lane >> 4;
    const int l15 = lane & 15;
    const int wsel = blockIdx.y;
    const int r0 = blockIdx.x * 64;
    const int arow = r0 + w * 16 + l15;

    // x -> hi/lo f16 A-fragments (on-the-fly conversion, no staging buffer)
    h8 Ahi[8], Alo[8];
#pragma unroll
    for (int ks = 0; ks < 8; ++ks) {
        float xv[8];
        *(float4*)&xv[0] = *(const float4*)&x[(size_t)arow * 256 + ks * 32 + quad * 8];
        *(float4*)&xv[4] = *(const float4*)&x[(size_t)arow * 256 + ks * 32 + quad * 8 + 4];
#pragma unroll
        for (int j = 0; j < 8; ++j) {
            const h1 hi = (h1)xv[j];
            Ahi[ks][j] = hi;
            Alo[ks][j] = (h1)(xv[j] - (float)hi);
        }
    }

    const h1* WTw = WT + (size_t)wsel * 65536;
    fx4 acc[16];
#pragma unroll
    for (int ct = 0; ct < 16; ++ct) acc[ct] = (fx4){0.f, 0.f, 0.f, 0.f};

#pragma unroll
    for (int ks = 0; ks < 8; ++ks) {
        h8 Bf[16];
#pragma unroll
        for (int ct = 0; ct < 16; ++ct)
            Bf[ct] = *(const h8*)&WTw[(size_t)(ct * 16 + l15) * 256 + ks * 32 + quad * 8];
#pragma unroll
        for (int ct = 0; ct < 16; ++ct) {
            acc[ct] = __builtin_amdgcn_mfma_f32_16x16x32_f16(Ahi[ks], Bf[ct], acc[ct], 0, 0, 0);
            acc[ct] = __builtin_amdgcn_mfma_f32_16x16x32_f16(Alo[ks], Bf[ct], acc[ct], 0, 0, 0);
        }
    }

    if (wsel < 2) {
        const float* bias = (wsel == 0) ? bq : bk;
        h1* f = (wsel == 0) ? fq : fk;
#pragma unroll
        for (int ct = 0; ct < 16; ++ct) {
            const int c = ct * 16 + l15;
            const float bb = bias[c];
            const int h = c >> 5, dd = c & 31;
#pragma unroll
            for (int r = 0; r < 4; ++r) {
                const int row = r0 + w * 16 + quad * 4 + r;
                const int b = row >> 11, n = row & (Nn - 1);
                float sv, cv;
                __sincosf(acc[ct][r] + bb, &sv, &cv);
                h1* fp = f + ((size_t)((b * Hn + h) * Nn + n)) * 64 + dd;
                fp[0]  = (h1)cv;
                fp[32] = (h1)sv;
            }
        }
    } else {
        // v: stage to LDS, cooperative transposed write (coalesced vT rows)
#pragma unroll
        for (int ct = 0; ct < 16; ++ct) {
            const int c = ct * 16 + l15;
            const float bb = bv[c];
#pragma unroll
            for (int r = 0; r < 4; ++r)
                vst[w * 16 + quad * 4 + r][c] = (h1)(acc[ct][r] + bb);
        }
        __syncthreads();
        const int c = tid;
        const int h = c >> 5, dd = c & 31;
        const int b = r0 >> 11, n0 = r0 & (Nn - 1);
        h1* vp = vT + ((size_t)((b * Hn + h) * HDn + dd)) * Nn + n0;
#pragma unroll
        for (int g = 0; g < 8; ++g) {
            h8 pk;
#pragma unroll
            for (int j = 0; j < 8; ++j) pk[j] = vst[g * 8 + j][c];
            *(h8*)(vp + g * 8) = pk;
        }
    }
}

// ---------------------------------------------------------------------------
// Kernel 2: fused attention, barrier-free, full occupancy.
// Wave = (b, h, 32 q-rows, m-quarter). Block = 4 waves (4 heads, same topo ->
// L1 hits). Grid 2048 blocks = 8 blocks/CU = 32 waves/CU. Fixed-shift softmax:
// no reductions in the loop; per-lane l partials reduced once in epilogue.
// ---------------------------------------------------------------------------
__global__ __launch_bounds__(256, 8) void attn_kernel(
    const h1* __restrict__ fq, const h1* __restrict__ fk, const h1* __restrict__ vT,
    const float* __restrict__ topo, float* __restrict__ pacc, float* __restrict__ pl)
{
    __shared__ __align__(16) h1 Pw[4][32][40];  // per-wave P transpose buffer

    const int b = blockIdx.y;
    const int n0 = blockIdx.x * 32;
    const int z = blockIdx.z;          // z = hg + 2*mq
    const int mq = z >> 1;
    const int tid = threadIdx.x;
    const int w = tid >> 6;
    const int h = (z & 1) * 4 + w;
    const int lane = tid & 63;
    const int quad = lane >> 4;
    const int l15 = lane & 15;

    const h1* qfh = fq + (size_t)(b * Hn + h) * Nn * 64;
    const h1* kfh = fk + (size_t)(b * Hn + h) * Nn * 64;
    const h1* vTh = vT + (size_t)(b * Hn + h) * HDn * Nn;
    const float* tpb = topo + (size_t)b * Nn * Nn + (size_t)n0 * Nn;

    h8 qfr[2][2];
#pragma unroll
    for (int qs = 0; qs < 2; ++qs)
#pragma unroll
        for (int ks = 0; ks < 2; ++ks)
            qfr[qs][ks] = *(const h8*)(qfh + (size_t)(n0 + qs * 16 + l15) * 64 + ks * 32 + quad * 8);

    fx4 acc[2][2];
    float lsum[2][4];
#pragma unroll
    for (int qs = 0; qs < 2; ++qs) {
#pragma unroll
        for (int ds = 0; ds < 2; ++ds) acc[qs][ds] = (fx4){0.f, 0.f, 0.f, 0.f};
#pragma unroll
        for (int r = 0; r < 4; ++r) lsum[qs][r] = 0.f;
    }

    const int mbase = mq * MQ;
    const fx4 z4 = {0.f, 0.f, 0.f, 0.f};

    for (int it = 0; it < MQ / 32; ++it) {
        const int m0 = mbase + it * 32;

        h8 kfr[2][2];
#pragma unroll
        for (int ms = 0; ms < 2; ++ms)
#pragma unroll
            for (int ks = 0; ks < 2; ++ks)
                kfr[ms][ks] = *(const h8*)(kfh + (size_t)(m0 + ms * 16 + l15) * 64 + ks * 32 + quad * 8);
        h8 bV[2];
#pragma unroll
        for (int ds = 0; ds < 2; ++ds)
            bV[ds] = *(const h8*)(vTh + (size_t)(ds * 16 + l15) * Nn + m0 + quad * 8);
        float tpv[2][4][2];
#pragma unroll
        for (int qs = 0; qs < 2; ++qs)
#pragma unroll
            for (int r = 0; r < 4; ++r) {
                const float* tr = tpb + (size_t)(qs * 16 + quad * 4 + r) * Nn + m0 + l15;
                tpv[qs][r][0] = tr[0]  * QSCALE;
                tpv[qs][r][1] = tr[16] * QSCALE;
            }

        fx4 S[2][2];
#pragma unroll
        for (int qs = 0; qs < 2; ++qs)
#pragma unroll
            for (int ms = 0; ms < 2; ++ms) {
                fx4 tmp = __builtin_amdgcn_mfma_f32_16x16x32_f16(qfr[qs][0], kfr[ms][0], z4, 0, 0, 0);
                S[qs][ms] = __builtin_amdgcn_mfma_f32_16x16x32_f16(qfr[qs][1], kfr[ms][1], tmp, 0, 0, 0);
            }

#pragma unroll
        for (int qs = 0; qs < 2; ++qs)
#pragma unroll
            for (int ms = 0; ms < 2; ++ms)
#pragma unroll
                for (int r = 0; r < 4; ++r) {
                    const float p = __expf(fmaf(S[qs][ms][r], tpv[qs][r][ms], -SOFTMAX_SHIFT));
                    lsum[qs][r] += p;
                    Pw[w][qs * 16 + quad * 4 + r][ms * 16 + l15] = (h1)p;
                }
        __asm__ volatile("s_waitcnt lgkmcnt(0)" ::: "memory");

        h8 aP[2];
#pragma unroll
        for (int qs = 0; qs < 2; ++qs)
            aP[qs] = *(const h8*)&Pw[w][qs * 16 + l15][quad * 8];
#pragma unroll
        for (int qs = 0; qs < 2; ++qs)
#pragma unroll
            for (int ds = 0; ds < 2; ++ds)
                acc[qs][ds] = __builtin_amdgcn_mfma_f32_16x16x32_f16(aP[qs], bV[ds], acc[qs][ds], 0, 0, 0);
    }

    // epilogue: reduce l across the 16 col-lanes, write partials
#pragma unroll
    for (int qs = 0; qs < 2; ++qs)
#pragma unroll
        for (int r = 0; r < 4; ++r)
#pragma unroll
            for (int off = 1; off <= 8; off <<= 1)
                lsum[qs][r] += __shfl_xor(lsum[qs][r], off);

    float* paccm = pacc + (size_t)mq * Bn * Nn * Dn;
    float* plm   = pl   + (size_t)mq * Bn * Nn * Hn;
#pragma unroll
    for (int qs = 0; qs < 2; ++qs)
#pragma unroll
        for (int r = 0; r < 4; ++r) {
            const size_t grow = (size_t)b * Nn + n0 + qs * 16 + quad * 4 + r;
            paccm[grow * Dn + h * HDn + l15]      = acc[qs][0][r];
            paccm[grow * Dn + h * HDn + 16 + l15] = acc[qs][1][r];
            if (l15 == 0) plm[grow * Hn + h] = lsum[qs][r];
        }
}

// ---------------------------------------------------------------------------
// Kernel 3: merge 4 partials + output projection. 8 rows/block, thread=col.
// ---------------------------------------------------------------------------
__global__ __launch_bounds__(256) void oproj_kernel(
    const float* __restrict__ pacc, const float* __restrict__ pl,
    const float* __restrict__ Wo, const float* __restrict__ bo,
    float* __restrict__ out)
{
    __shared__ float ysT[256][12];  // [col][row], float4-aligned rows
    const int t = threadIdx.x;
    const int r0 = blockIdx.x * 8;
    const int h = t >> 5;
    const size_t PACC = (size_t)Bn * Nn * Dn;
    const size_t PL = (size_t)Bn * Nn * Hn;
#pragma unroll
    for (int i = 0; i < 8; ++i) {
        const size_t row = (size_t)(r0 + i);
        float l = 0.f, yv = 0.f;
#pragma unroll
        for (int m = 0; m < 4; ++m) {
            l  += pl[m * PL + row * Hn + h];
            yv += pacc[m * PACC + row * Dn + t];
        }
        ysT[t][i] = yv * __builtin_amdgcn_rcpf(l);
    }
    __syncthreads();

    float acc8[8];
#pragma unroll
    for (int i = 0; i < 8; ++i) acc8[i] = 0.f;
#pragma unroll 4
    for (int d = 0; d < 256; ++d) {
        const float wv = Wo[d * 256 + t];
        float yy[8];
        *(float4*)&yy[0] = *(const float4*)&ysT[d][0];  // broadcast reads
        *(float4*)&yy[4] = *(const float4*)&ysT[d][4];
#pragma unroll
        for (int i = 0; i < 8; ++i) acc8[i] = fmaf(yy[i], wv, acc8[i]);
    }
    const float bb = bo[t];
#pragma unroll
    for (int i = 0; i < 8; ++i)
        out[(size_t)(r0 + i) * 256 + t] = acc8[i] + bb;
}

// ---------------------------------------------------------------------------
extern "C" void kernel_launch(void* const* d_in, const int* in_sizes, int n_in,
                              void* d_out, int out_size, void* d_ws, size_t ws_size,
                              hipStream_t stream)
{
    const float* x    = (const float*)d_in[0];
    const float* topo = (const float*)d_in[1];
    const float* Wq   = (const float*)d_in[2];
    const float* bq   = (const float*)d_in[3];
    const float* Wk   = (const float*)d_in[4];
    const float* bk   = (const float*)d_in[5];
    const float* Wv   = (const float*)d_in[6];
    const float* bv   = (const float*)d_in[7];
    const float* Wo   = (const float*)d_in[8];
    const float* bo   = (const float*)d_in[9];
    float* out = (float*)d_out;

    char* ws = (char*)d_ws;
    const size_t MB = 1024 * 1024;
    // ws: WT 0.4MB @0 | fq 8MB @1 | fk 8MB @9 | vT 4MB @17 | pacc 32MB @21 | pl 1MB @53
    h1* WT = (h1*)ws;
    h1* fq = (h1*)(ws + 1 * MB);
    h1* fk = (h1*)(ws + 9 * MB);
    h1* vT = (h1*)(ws + 17 * MB);
    float* pacc = (float*)(ws + 21 * MB);
    float* pl   = (float*)(ws + 53 * MB);

    cvtW_kernel<<<768, 256, 0, stream>>>(Wq, Wk, Wv, WT);
    proj_kernel<<<dim3(128, 3), 256, 0, stream>>>(x, WT, bq, bk, bv, fq, fk, vT);
    attn_kernel<<<dim3(Nn / 32, Bn, 8), 256, 0, stream>>>(fq, fk, vT, topo, pacc, pl);
    oproj_kernel<<<(Bn * Nn) / 8, 256, 0, stream>>>(pacc, pl, Wo, bo, out);
}

// Round 4
// 287.828 us; speedup vs baseline: 1.4928x; 1.4928x over previous
//
#include <hip/hip_runtime.h>
#include <math.h>

#define Bn 4
#define Nn 2048
#define Hn 8
#define HDn 32
#define Dn 256
#define MHALF 1024  // m-split: 2 partials merged in oproj

typedef _Float16 h1;
typedef __attribute__((ext_vector_type(8))) _Float16 h8;
typedef __attribute__((ext_vector_type(4))) float fx4;

#define QSCALE 0.35355339059327373f  // 2/sqrt(HD): applied at exp time
// |S_raw| <= HD = 32, |S_raw*QSCALE*topo| <= 11.32 -> fixed softmax shift safe:
// p = e^{S-4} in [2.2e-7, 1503] -- fits f16, no running max needed.
#define SOFTMAX_SHIFT 4.0f

// ---------------------------------------------------------------------------
// Kernel 0: transpose weights to f16  WT[w][out][d]  (w: 0=q,1=k,2=v)
// ---------------------------------------------------------------------------
__global__ __launch_bounds__(256) void cvtW_kernel(
    const float* __restrict__ Wq, const float* __restrict__ Wk,
    const float* __restrict__ Wv, h1* __restrict__ WT)
{
    const int idx = blockIdx.x * 256 + threadIdx.x;  // 3*65536
    const int o = idx & 255;
    const int d = (idx >> 8) & 255;
    const int w = idx >> 16;
    const float* W = (w == 0) ? Wq : (w == 1) ? Wk : Wv;
    WT[(size_t)w * 65536 + o * 256 + d] = (h1)W[d * 256 + o];
}

// ---------------------------------------------------------------------------
// Kernel 1: QKV projection via f16 MFMA (x split hi/lo for ~f32 accuracy)
// Block = 4 waves x 16 rows = 64 rows x 256 cols of ONE W (grid.y selects).
// Epilogue: q/k -> sincos features (unscaled); v -> LDS transpose -> vT.
// Fragment layouts (verified gfx950):
//   A: A[m=lane&15][k=quad*8+j], B: B[k=quad*8+j][n=lane&15],
//   C/D: row=quad*4+reg, col=lane&15
// ---------------------------------------------------------------------------
__global__ __launch_bounds__(256, 2) void proj_kernel(
    const float* __restrict__ x, const h1* __restrict__ WT,
    const float* __restrict__ bq, const float* __restrict__ bk,
    const float* __restrict__ bv,
    h1* __restrict__ fq, h1* __restrict__ fk, h1* __restrict__ vT)
{
    __shared__ h1 vst[64][264];  // v transpose buffer (pad 264: 2-way free)
    const int tid = threadIdx.x;
    const int w = tid >> 6;
    const int lane = tid & 63;
    const int quad = lane >> 4;
    const int l15 = lane & 15;
    const int wsel = blockIdx.y;
    const int r0 = blockIdx.x * 64;
    const int arow = r0 + w * 16 + l15;

    // x -> hi/lo f16 A-fragments (on-the-fly conversion, no staging buffer)
    h8 Ahi[8], Alo[8];
#pragma unroll
    for (int ks = 0; ks < 8; ++ks) {
        float xv[8];
        *(float4*)&xv[0] = *(const float4*)&x[(size_t)arow * 256 + ks * 32 + quad * 8];
        *(float4*)&xv[4] = *(const float4*)&x[(size_t)arow * 256 + ks * 32 + quad * 8 + 4];
#pragma unroll
        for (int j = 0; j < 8; ++j) {
            const h1 hi = (h1)xv[j];
            Ahi[ks][j] = hi;
            Alo[ks][j] = (h1)(xv[j] - (float)hi);
        }
    }

    const h1* WTw = WT + (size_t)wsel * 65536;
    fx4 acc[16];
#pragma unroll
    for (int ct = 0; ct < 16; ++ct) acc[ct] = (fx4){0.f, 0.f, 0.f, 0.f};

#pragma unroll
    for (int ks = 0; ks < 8; ++ks) {
        h8 Bf[16];
#pragma unroll
        for (int ct = 0; ct < 16; ++ct)
            Bf[ct] = *(const h8*)&WTw[(size_t)(ct * 16 + l15) * 256 + ks * 32 + quad * 8];
#pragma unroll
        for (int ct = 0; ct < 16; ++ct) {
            acc[ct] = __builtin_amdgcn_mfma_f32_16x16x32_f16(Ahi[ks], Bf[ct], acc[ct], 0, 0, 0);
            acc[ct] = __builtin_amdgcn_mfma_f32_16x16x32_f16(Alo[ks], Bf[ct], acc[ct], 0, 0, 0);
        }
    }

    if (wsel < 2) {
        const float* bias = (wsel == 0) ? bq : bk;
        h1* f = (wsel == 0) ? fq : fk;
#pragma unroll
        for (int ct = 0; ct < 16; ++ct) {
            const int c = ct * 16 + l15;
            const float bb = bias[c];
            const int h = c >> 5, dd = c & 31;
#pragma unroll
            for (int r = 0; r < 4; ++r) {
                const int row = r0 + w * 16 + quad * 4 + r;
                const int b = row >> 11, n = row & (Nn - 1);
                float sv, cv;
                __sincosf(acc[ct][r] + bb, &sv, &cv);
                h1* fp = f + ((size_t)((b * Hn + h) * Nn + n)) * 64 + dd;
                fp[0]  = (h1)cv;
                fp[32] = (h1)sv;
            }
        }
    } else {
        // v: stage to LDS, cooperative transposed write (coalesced vT rows)
#pragma unroll
        for (int ct = 0; ct < 16; ++ct) {
            const int c = ct * 16 + l15;
            const float bb = bv[c];
#pragma unroll
            for (int r = 0; r < 4; ++r)
                vst[w * 16 + quad * 4 + r][c] = (h1)(acc[ct][r] + bb);
        }
        __syncthreads();
        const int c = tid;
        const int h = c >> 5, dd = c & 31;
        const int b = r0 >> 11, n0 = r0 & (Nn - 1);
        h1* vp = vT + ((size_t)((b * Hn + h) * HDn + dd)) * Nn + n0;
#pragma unroll
        for (int g = 0; g < 8; ++g) {
            h8 pk;
#pragma unroll
            for (int j = 0; j < 8; ++j) pk[j] = vst[g * 8 + j][c];
            *(h8*)(vp + g * 8) = pk;
        }
    }
}

// ---------------------------------------------------------------------------
// Kernel 2: fused attention, barrier-free, software-pipelined.
// Wave = (b, h, 32 q-rows, m-half). Block = 4 waves = 4 heads (same topo ->
// L1/L2 hits). Grid 1024 blocks = 4 blocks/CU (VGPR cap 128: no spills).
// Depth-1 prefetch: tile it+1's kf/vT/topo loads issue before tile it's
// compute -> hides the ~900-cyc HBM latency of the topo stream.
// Fixed-shift softmax: no reductions in the loop.
// ---------------------------------------------------------------------------
__global__ __launch_bounds__(256, 4) void attn_kernel(
    const h1* __restrict__ fq, const h1* __restrict__ fk, const h1* __restrict__ vT,
    const float* __restrict__ topo, float* __restrict__ pacc, float* __restrict__ pl)
{
    __shared__ __align__(16) h1 Pw[4][32][40];  // per-wave P transpose buffer

    const int b = blockIdx.y;
    const int n0 = blockIdx.x * 32;
    const int z = blockIdx.z;          // z = hg + 2*mh
    const int mh = z >> 1;
    const int tid = threadIdx.x;
    const int w = tid >> 6;
    const int h = (z & 1) * 4 + w;
    const int lane = tid & 63;
    const int quad = lane >> 4;
    const int l15 = lane & 15;

    const h1* qfh = fq + (size_t)(b * Hn + h) * Nn * 64;
    const h1* kfh = fk + (size_t)(b * Hn + h) * Nn * 64;
    const h1* vTh = vT + (size_t)(b * Hn + h) * HDn * Nn;
    const float* tpb = topo + (size_t)b * Nn * Nn + (size_t)n0 * Nn;

    h8 qfr[2][2];
#pragma unroll
    for (int qs = 0; qs < 2; ++qs)
#pragma unroll
        for (int ks = 0; ks < 2; ++ks)
            qfr[qs][ks] = *(const h8*)(qfh + (size_t)(n0 + qs * 16 + l15) * 64 + ks * 32 + quad * 8);

    fx4 acc[2][2];
    float lsum[2][4];
#pragma unroll
    for (int qs = 0; qs < 2; ++qs) {
#pragma unroll
        for (int ds = 0; ds < 2; ++ds) acc[qs][ds] = (fx4){0.f, 0.f, 0.f, 0.f};
#pragma unroll
        for (int r = 0; r < 4; ++r) lsum[qs][r] = 0.f;
    }

    const int mbase = mh * MHALF;
    const fx4 z4 = {0.f, 0.f, 0.f, 0.f};

#define LOAD_TILE(KF, BV, TP, M0)                                              \
    do {                                                                       \
        _Pragma("unroll") for (int ms = 0; ms < 2; ++ms)                       \
            _Pragma("unroll") for (int ks = 0; ks < 2; ++ks)                   \
                KF[ms][ks] = *(const h8*)(kfh +                                \
                    (size_t)((M0) + ms * 16 + l15) * 64 + ks * 32 + quad * 8); \
        _Pragma("unroll") for (int ds = 0; ds < 2; ++ds)                       \
            BV[ds] = *(const h8*)(vTh +                                        \
                (size_t)(ds * 16 + l15) * Nn + (M0) + quad * 8);               \
        _Pragma("unroll") for (int qs = 0; qs < 2; ++qs)                       \
            _Pragma("unroll") for (int r = 0; r < 4; ++r) {                    \
                const float* tr = tpb +                                        \
                    (size_t)(qs * 16 + quad * 4 + r) * Nn + (M0) + l15;        \
                TP[qs][r][0] = tr[0];                                          \
                TP[qs][r][1] = tr[16];                                         \
            }                                                                  \
    } while (0)

    h8 kf_c[2][2], kf_n[2][2], bV_c[2], bV_n[2];
    float tp_c[2][4][2], tp_n[2][4][2];
    LOAD_TILE(kf_c, bV_c, tp_c, mbase);

    for (int it = 0; it < MHALF / 32; ++it) {
        // prefetch tile it+1 (clamped on last iter; results then unused)
        const int mnext = mbase + ((it < MHALF / 32 - 1) ? (it + 1) * 32
                                                         : (MHALF / 32 - 1) * 32);
        LOAD_TILE(kf_n, bV_n, tp_n, mnext);

        // S = Qf @ Kf^T on current tile
        fx4 S[2][2];
#pragma unroll
        for (int qs = 0; qs < 2; ++qs)
#pragma unroll
            for (int ms = 0; ms < 2; ++ms) {
                fx4 tmp = __builtin_amdgcn_mfma_f32_16x16x32_f16(qfr[qs][0], kf_c[ms][0], z4, 0, 0, 0);
                S[qs][ms] = __builtin_amdgcn_mfma_f32_16x16x32_f16(qfr[qs][1], kf_c[ms][1], tmp, 0, 0, 0);
            }

        // p = e^{S*topo*QSCALE - 4}; per-lane l partials; P -> LDS (C->A)
#pragma unroll
        for (int qs = 0; qs < 2; ++qs)
#pragma unroll
            for (int ms = 0; ms < 2; ++ms)
#pragma unroll
                for (int r = 0; r < 4; ++r) {
                    const float ts = S[qs][ms][r] * tp_c[qs][r][ms];
                    const float p = __expf(fmaf(ts, QSCALE, -SOFTMAX_SHIFT));
                    lsum[qs][r] += p;
                    Pw[w][qs * 16 + quad * 4 + r][ms * 16 + l15] = (h1)p;
                }
        __asm__ volatile("s_waitcnt lgkmcnt(0)" ::: "memory");

        h8 aP[2];
#pragma unroll
        for (int qs = 0; qs < 2; ++qs)
            aP[qs] = *(const h8*)&Pw[w][qs * 16 + l15][quad * 8];
#pragma unroll
        for (int qs = 0; qs < 2; ++qs)
#pragma unroll
            for (int ds = 0; ds < 2; ++ds)
                acc[qs][ds] = __builtin_amdgcn_mfma_f32_16x16x32_f16(aP[qs], bV_c[ds], acc[qs][ds], 0, 0, 0);

        // rotate pipeline registers
#pragma unroll
        for (int ms = 0; ms < 2; ++ms) {
            kf_c[ms][0] = kf_n[ms][0];
            kf_c[ms][1] = kf_n[ms][1];
        }
        bV_c[0] = bV_n[0];
        bV_c[1] = bV_n[1];
#pragma unroll
        for (int qs = 0; qs < 2; ++qs)
#pragma unroll
            for (int r = 0; r < 4; ++r) {
                tp_c[qs][r][0] = tp_n[qs][r][0];
                tp_c[qs][r][1] = tp_n[qs][r][1];
            }
    }
#undef LOAD_TILE

    // epilogue: reduce l across the 16 col-lanes, write partials
#pragma unroll
    for (int qs = 0; qs < 2; ++qs)
#pragma unroll
        for (int r = 0; r < 4; ++r)
#pragma unroll
            for (int off = 1; off <= 8; off <<= 1)
                lsum[qs][r] += __shfl_xor(lsum[qs][r], off);

    float* paccm = pacc + (size_t)mh * Bn * Nn * Dn;
    float* plm   = pl   + (size_t)mh * Bn * Nn * Hn;
#pragma unroll
    for (int qs = 0; qs < 2; ++qs)
#pragma unroll
        for (int r = 0; r < 4; ++r) {
            const size_t grow = (size_t)b * Nn + n0 + qs * 16 + quad * 4 + r;
            paccm[grow * Dn + h * HDn + l15]      = acc[qs][0][r];
            paccm[grow * Dn + h * HDn + 16 + l15] = acc[qs][1][r];
            if (l15 == 0) plm[grow * Hn + h] = lsum[qs][r];
        }
}

// ---------------------------------------------------------------------------
// Kernel 3: merge 2 partials + output projection. 8 rows/block, thread=col.
// ---------------------------------------------------------------------------
__global__ __launch_bounds__(256) void oproj_kernel(
    const float* __restrict__ pacc, const float* __restrict__ pl,
    const float* __restrict__ Wo, const float* __restrict__ bo,
    float* __restrict__ out)
{
    __shared__ float ysT[256][12];  // [col][row], float4-aligned rows
    const int t = threadIdx.x;
    const int r0 = blockIdx.x * 8;
    const int h = t >> 5;
    const size_t PACC = (size_t)Bn * Nn * Dn;
    const size_t PL = (size_t)Bn * Nn * Hn;
#pragma unroll
    for (int i = 0; i < 8; ++i) {
        const size_t row = (size_t)(r0 + i);
        float l = 0.f, yv = 0.f;
#pragma unroll
        for (int m = 0; m < 2; ++m) {
            l  += pl[m * PL + row * Hn + h];
            yv += pacc[m * PACC + row * Dn + t];
        }
        ysT[t][i] = yv * __builtin_amdgcn_rcpf(l);
    }
    __syncthreads();

    float acc8[8];
#pragma unroll
    for (int i = 0; i < 8; ++i) acc8[i] = 0.f;
#pragma unroll 4
    for (int d = 0; d < 256; ++d) {
        const float wv = Wo[d * 256 + t];
        float yy[8];
        *(float4*)&yy[0] = *(const float4*)&ysT[d][0];  // broadcast reads
        *(float4*)&yy[4] = *(const float4*)&ysT[d][4];
#pragma unroll
        for (int i = 0; i < 8; ++i) acc8[i] = fmaf(yy[i], wv, acc8[i]);
    }
    const float bb = bo[t];
#pragma unroll
    for (int i = 0; i < 8; ++i)
        out[(size_t)(r0 + i) * 256 + t] = acc8[i] + bb;
}

// ---------------------------------------------------------------------------
extern "C" void kernel_launch(void* const* d_in, const int* in_sizes, int n_in,
                              void* d_out, int out_size, void* d_ws, size_t ws_size,
                              hipStream_t stream)
{
    const float* x    = (const float*)d_in[0];
    const float* topo = (const float*)d_in[1];
    const float* Wq   = (const float*)d_in[2];
    const float* bq   = (const float*)d_in[3];
    const float* Wk   = (const float*)d_in[4];
    const float* bk   = (const float*)d_in[5];
    const float* Wv   = (const float*)d_in[6];
    const float* bv   = (const float*)d_in[7];
    const float* Wo   = (const float*)d_in[8];
    const float* bo   = (const float*)d_in[9];
    float* out = (float*)d_out;

    char* ws = (char*)d_ws;
    const size_t MB = 1024 * 1024;
    // ws: WT 0.4MB @0 | fq 8MB @1 | fk 8MB @9 | vT 4MB @17 | pacc 16MB @21 | pl 0.5MB @37
    h1* WT = (h1*)ws;
    h1* fq = (h1*)(ws + 1 * MB);
    h1* fk = (h1*)(ws + 9 * MB);
    h1* vT = (h1*)(ws + 17 * MB);
    float* pacc = (float*)(ws + 21 * MB);
    float* pl   = (float*)(ws + 37 * MB);

    cvtW_kernel<<<768, 256, 0, stream>>>(Wq, Wk, Wv, WT);
    proj_kernel<<<dim3(128, 3), 256, 0, stream>>>(x, WT, bq, bk, bv, fq, fk, vT);
    attn_kernel<<<dim3(Nn / 32, Bn, 4), 256, 0, stream>>>(fq, fk, vT, topo, pacc, pl);
    oproj_kernel<<<(Bn * Nn) / 8, 256, 0, stream>>>(pacc, pl, Wo, bo, out);
}